// Round 18
// baseline (117.638 us; speedup 1.0000x reference)
//
#include <hip/hip_runtime.h>
#include <hip/hip_bf16.h>
#include <cstdint>
#include <cstddef>

#define NN 100000
#define NE 1600000
#define KD 256
#define OD 128
#define NB 391      // ceil(NN/256) buckets of 256 src nodes (place/aggr CSR)
#define CAP 8192    // staging capacity per bucket (mean 6250, sigma ~79)
#define PCAP 9984   // padded CSR region per bucket (CAP + 256*7)
#define NGB 391     // gemm blocks in fused kernel (256 rows each, 1024 thr)
#define NBIN 121    // bin blocks; grid-stride over 391 batches of 4096 edges
#define NBATCH 391  // edge batches (391*4096 >= 1.6M)

typedef __attribute__((ext_vector_type(8))) __bf16 bf16x8;
typedef __attribute__((ext_vector_type(4))) float f32x4;
typedef __attribute__((ext_vector_type(8))) unsigned short ushort8;

static __device__ __forceinline__ unsigned short f2bf(float f) {
  return __builtin_bit_cast(unsigned short, (__bf16)f);
}

// ---------------- kernel 1: W -> Wt bf16 transposed; also init bcur ---------------
__global__ void prep_wt_k(const float* __restrict__ W, unsigned short* __restrict__ Wt,
                          int* __restrict__ bcur) {
  const int i = blockIdx.x * 256 + threadIdx.x;  // 32768 total
  const int k = i >> 7;   // 0..255
  const int n = i & 127;  // 0..127
  Wt[n * KD + k] = f2bf(W[i]);
  if (i < NB) bcur[i] = i * CAP;
}

// ---------------- kernel 2: FUSED  gemm (blocks 0..390) | bin (391..511) ----------
// gemm: 1024 thr = 16 waves, 256 rows/block, whole Wt in LDS (XOR-swizzled).
//       2-stage x-load rotation: k-step s+1's loads issue before s's MFMAs -> one
//       load latency hidden per step. LB(1024,4) gives VGPR room (occupancy is
//       LDS-limited at 2 blocks/CU either way, so the relaxation is free).
// bin : 121 blocks grid-striding 391 batches of 4096 edges (LDS sort per batch).
__global__ __launch_bounds__(1024, 4) void fused_k(
    const float* __restrict__ x, const unsigned short* __restrict__ Wt,
    const float* __restrict__ a, unsigned short* __restrict__ h,
    float* __restrict__ ssrc, float* __restrict__ sdst,
    const int* __restrict__ el, int* __restrict__ bcur,
    unsigned* __restrict__ stage) {
  __shared__ alignas(16) char smem[65536];
  const int t = threadIdx.x;

  if (blockIdx.x < NGB) {
    // ------------------------- GEMM part -------------------------
    unsigned short* Bl = (unsigned short*)smem;  // 128 rows x 512 B, swizzled
#pragma unroll
    for (int it = 0; it < 4; ++it) {
      const int c = it * 1024 + t;       // 4096 chunks of 16 B
      const int r = c >> 5;
      const int c16 = c & 31;
      const ushort8 v = *(const ushort8*)(Wt + r * 256 + c16 * 8);
      const int byt = (r * 512 + c16 * 16) ^ ((r & 7) << 4);
      *(ushort8*)((char*)Bl + byt) = v;
    }
    const int lane = t & 63;
    const int wave = t >> 6;             // 0..15
    const int col = lane & 15;
    const int kg = lane >> 4;
    const int m0 = blockIdx.x * 256 + wave * 16;
    const int arow = m0 + col;
    const bool rowok = arow < NN;
    const float* __restrict__ xrow = x + (size_t)arow * KD;

    // prologue: stage A = k-step 0 loads (issued before the barrier wait)
    const float4 z4 = make_float4(0.f, 0.f, 0.f, 0.f);
    float4 c0 = rowok ? *(const float4*)(xrow + kg * 8)     : z4;
    float4 c1 = rowok ? *(const float4*)(xrow + kg * 8 + 4) : z4;
    __syncthreads();

    f32x4 acc[8];
#pragma unroll
    for (int i = 0; i < 8; ++i) acc[i] = (f32x4)0.0f;

#pragma unroll
    for (int s = 0; s < 8; ++s) {
      // issue k-step s+1's loads before consuming s (2-stage rotation)
      float4 n0, n1;
      if (s < 7) {
        const int kk = (s + 1) * 32 + kg * 8;
        n0 = rowok ? *(const float4*)(xrow + kk)     : z4;
        n1 = rowok ? *(const float4*)(xrow + kk + 4) : z4;
      }
      bf16x8 af;
      af[0] = (__bf16)c0.x; af[1] = (__bf16)c0.y; af[2] = (__bf16)c0.z; af[3] = (__bf16)c0.w;
      af[4] = (__bf16)c1.x; af[5] = (__bf16)c1.y; af[6] = (__bf16)c1.z; af[7] = (__bf16)c1.w;
#pragma unroll
      for (int nt = 0; nt < 8; ++nt) {
        const int n = nt * 16 + col;
        const int byt = (n * 512 + s * 64 + kg * 16) ^ ((col & 7) << 4);
        const ushort8 bu = *(const ushort8*)((const char*)Bl + byt);
        const bf16x8 bf = __builtin_bit_cast(bf16x8, bu);
        acc[nt] = __builtin_amdgcn_mfma_f32_16x16x32_bf16(af, bf, acc[nt], 0, 0, 0);
      }
      if (s < 7) { c0 = n0; c1 = n1; }
    }

    // C/D layout: col = lane&15, row = (lane>>4)*4 + r
    float ps[4] = {0.f, 0.f, 0.f, 0.f};
    float pd[4] = {0.f, 0.f, 0.f, 0.f};
#pragma unroll
    for (int nt = 0; nt < 8; ++nt) {
      const int n = nt * 16 + col;
      const float av = a[n];
      const float av2 = a[OD + n];
#pragma unroll
      for (int r = 0; r < 4; ++r) {
        const float v = acc[nt][r];
        const int row = m0 + kg * 4 + r;
        if (row < NN) h[(size_t)row * OD + n] = f2bf(v);
        ps[r] += v * av;
        pd[r] += v * av2;
      }
    }
#pragma unroll
    for (int off = 1; off < 16; off <<= 1) {
#pragma unroll
      for (int r = 0; r < 4; ++r) {
        ps[r] += __shfl_xor(ps[r], off, 64);
        pd[r] += __shfl_xor(pd[r], off, 64);
      }
    }
    if (col == 0) {
#pragma unroll
      for (int r = 0; r < 4; ++r) {
        const int row = m0 + kg * 4 + r;
        // pre-scale scores by log2(e): weight pass uses exp2 (leaky commutes w/ scale)
        if (row < NN) {
          ssrc[row] = ps[r] * 1.442695041f;
          sdst[row] = pd[r] * 1.442695041f;
        }
      }
    }
  } else {
    // ------------------------- BIN part -------------------------
    unsigned* sorted = (unsigned*)smem;                       // 16384 B
    unsigned short* bkid = (unsigned short*)(smem + 16384);   // 8192 B
    int* hist  = (int*)(smem + 24576);                        // 392*4
    int* off   = (int*)(smem + 26144);                        // 392*4
    int* cur   = (int*)(smem + 27712);                        // 391*4
    int* delta = (int*)(smem + 29276);                        // 391*4
    for (int batch = (int)blockIdx.x - NGB; batch < NBATCH; batch += NBIN) {
      __syncthreads();  // protect LDS reuse across batches (no-op first pass)
      const int te = batch * 4096 + t * 4;
      int s[4], d[4];
      bool valid[4];
#pragma unroll
      for (int u = 0; u < 4; ++u) valid[u] = (te + u) < NE;
      if (te + 3 < NE) {
        const int4 a0 = *(const int4*)(el + te);
        const int4 b0 = *(const int4*)(el + NE + te);
        s[0] = a0.x; s[1] = a0.y; s[2] = a0.z; s[3] = a0.w;
        d[0] = b0.x; d[1] = b0.y; d[2] = b0.z; d[3] = b0.w;
      } else {
#pragma unroll
        for (int u = 0; u < 4; ++u) {
          s[u] = valid[u] ? el[te + u] : 0;
          d[u] = valid[u] ? el[NE + te + u] : 0;
        }
      }
      for (int i = t; i <= NB; i += 1024) hist[i] = 0;
      __syncthreads();
#pragma unroll
      for (int u = 0; u < 4; ++u)
        if (valid[u]) atomicAdd(&hist[s[u] >> 8], 1);
      __syncthreads();
      // exclusive scan of hist[0..NB] by wave 0 (7 entries/lane)
      if (t < 64) {
        int v[7];
        int sum = 0;
#pragma unroll
        for (int i = 0; i < 7; ++i) {
          const int idx = t * 7 + i;
          v[i] = (idx <= NB) ? hist[idx] : 0;
          sum += v[i];
        }
        int pre = sum;
#pragma unroll
        for (int o = 1; o < 64; o <<= 1) {
          const int nb = __shfl_up(pre, o, 64);
          if (t >= o) pre += nb;
        }
        pre -= sum;  // exclusive across lanes
        int run = pre;
#pragma unroll
        for (int i = 0; i < 7; ++i) {
          const int idx = t * 7 + i;
          if (idx <= NB) off[idx] = run;
          run += v[i];
        }
      }
      __syncthreads();
      for (int i = t; i < NB; i += 1024) cur[i] = off[i];
      __syncthreads();
#pragma unroll
      for (int u = 0; u < 4; ++u)
        if (valid[u]) {
          const int b = s[u] >> 8;
          const int p = atomicAdd(&cur[b], 1);
          sorted[p] = ((unsigned)(s[u] & 255) << 17) | (unsigned)d[u];
          bkid[p] = (unsigned short)b;
        }
      __syncthreads();
      for (int b = t; b < NB; b += 1024) {
        const int len = off[b + 1] - off[b];
        if (len > 0) {
          const int gb = atomicAdd(&bcur[b], len);
          delta[b] = gb - off[b];
        }
      }
      __syncthreads();
      const int n = off[NB];
      for (int i = t; i < n; i += 1024) {
        const int b = bkid[i];
        const int pos = delta[b] + i;
        if (pos < (b + 1) * CAP) stage[pos] = sorted[i];  // overflow clamp (never hit)
      }
    }
  }
}

// ---------------- kernel 3: per-bucket LDS hist/scan + weight + padded place ------
// CSR region per bucket is fixed: [b*PCAP, (b+1)*PCAP). Each node's run is padded
// to a multiple of 8 with {w=0, dst=first dst of run} so aggr has no bounds logic.
// entry = (bf15(exp2(leaky(ssrc[s]+sdst[d])))<<17) | dst   (w>0 -> 15 bits suffice)
__global__ __launch_bounds__(256) void place2_k(const unsigned* __restrict__ stage,
                                                const int* __restrict__ bcur,
                                                const float* __restrict__ ssrc,
                                                const float* __restrict__ sdst,
                                                unsigned* __restrict__ csrw,
                                                uint2* __restrict__ rc) {
  __shared__ unsigned ebuf[CAP];   // 32 KB
  __shared__ float sl[256];
  __shared__ int hist2[256];
  __shared__ int exc[256];
  __shared__ int cur2[256];
  __shared__ unsigned firstd[256];
  const int b = blockIdx.x;
  const int t = threadIdx.x;
  const int node = b * 256 + t;
  const int base = b * PCAP;
  int tot = bcur[b] - b * CAP;
  tot = tot > CAP ? CAP : tot;
  hist2[t] = 0;
  sl[t] = (node < NN) ? ssrc[node] : 0.f;
  for (int i = t; i < tot; i += 256) ebuf[i] = stage[(size_t)b * CAP + i];
  __syncthreads();
  for (int i = t; i < tot; i += 256) atomicAdd(&hist2[ebuf[i] >> 17], 1);
  __syncthreads();
  // exclusive scan of PADDED counts by wave 0 (4/lane)
  if (t < 64) {
    int p[4];
    int sum = 0;
#pragma unroll
    for (int i = 0; i < 4; ++i) {
      const int c = hist2[t * 4 + i];
      p[i] = (c + 7) & ~7;  // 0 stays 0
      sum += p[i];
    }
    int pre = sum;
#pragma unroll
    for (int o = 1; o < 64; o <<= 1) {
      const int nb = __shfl_up(pre, o, 64);
      if (t >= o) pre += nb;
    }
    pre -= sum;
    int run = pre;
#pragma unroll
    for (int i = 0; i < 4; ++i) { exc[t * 4 + i] = run; run += p[i]; }
  }
  __syncthreads();
  const int c = hist2[t];
  const int pc = (c + 7) & ~7;
  if (node < NN) rc[node] = make_uint2((unsigned)pc, (unsigned)(base + exc[t]));
  cur2[t] = exc[t];
  __syncthreads();
  for (int i = t; i < tot; i += 256) {
    const unsigned u = ebuf[i];
    const int s = u >> 17;
    const unsigned d = u & 0x1ffffu;
    const float sv = sl[s] + sdst[d];                 // log2-domain score
    const float w = exp2f(fmaxf(sv, 0.2f * sv));      // leaky+exp, w > 0
    unsigned wb = __builtin_bit_cast(unsigned, w);
    wb += 0x7fffu + ((wb >> 16) & 1u);                // round-to-nearest bf16
    const unsigned ent = ((wb >> 16) << 17) | d;      // sign bit is 0 -> 15 bits
    const int p = atomicAdd(&cur2[s], 1);
    if (p == exc[s]) firstd[s] = d;                   // capture a hot pad target
    csrw[base + p] = ent;
  }
  __syncthreads();
  // pad each run to multiple of 8 with {w=0, dst=firstd} (row stays L1/L2-hot)
  if (c > 0) {
    const unsigned padent = firstd[t];                // weight bits = 0 -> w = 0.0f
    const int e0 = exc[t];
    for (int i = c; i < pc; ++i) csrw[base + e0 + i] = padent;
  }
}

// ---------------- kernel 4: wave-per-node aggregate, dot2 inner loop --------------
// lane-group g = lane>>4 handles edge slot g; lane sub = lane&15 covers cols sub*8..+7
__global__ __launch_bounds__(256) void aggr_k(
    const unsigned short* __restrict__ h, const unsigned* __restrict__ csrw,
    const uint2* __restrict__ rc, float* __restrict__ out) {
  const int lane = threadIdx.x & 63;
  const int g = lane >> 4;
  const int sub = lane & 15;
  const int node = blockIdx.x * 4 + (threadIdx.x >> 6);  // grid covers exactly NN
  const uint2 rcv = rc[node];
  const int pdeg = (int)rcv.x;                 // padded degree (multiple of 8)
  const int r0 = (int)rcv.y;
  const uint4* __restrict__ hp = (const uint4*)h;  // one h row = 16 uint4
  float acc[8] = {0.f, 0.f, 0.f, 0.f, 0.f, 0.f, 0.f, 0.f};
  float sw = 0.f;
  const unsigned losel = 0x05040100u;   // [e0.lo16 | e1.lo16]
  const unsigned hisel = 0x07060302u;   // [e0.hi16 | e1.hi16]
  const unsigned onepk = 0x3F803F80u;   // packed bf16 (1.0, 1.0)
  const int nit = pdeg >> 3;  // 8 edges per iteration (4 groups x 2 slots)
  if (nit > 0) {
    int j = r0 + g;
    unsigned uA0 = csrw[j];
    unsigned uA1 = csrw[j + 4];
    uint4 pA0 = hp[(uA0 & 0x1ffffu) * 16u + sub];
    uint4 pA1 = hp[(uA1 & 0x1ffffu) * 16u + sub];
    for (int it = 0; it < nit; ++it) {
      unsigned uB0, uB1;
      uint4 pB0, pB1;
      const bool more = (it + 1) < nit;
      if (more) {
        j += 8;
        uB0 = csrw[j];
        uB1 = csrw[j + 4];
        pB0 = hp[(uB0 & 0x1ffffu) * 16u + sub];
        pB1 = hp[(uB1 & 0x1ffffu) * 16u + sub];
      }
      const unsigned wpk = (uA0 >> 17) | ((uA1 >> 17) << 16);  // bf16 pair (w0,w1)
      asm("v_dot2_f32_bf16 %0, %1, %2, %0" : "+v"(sw) : "v"(wpk), "v"(onepk));
      const unsigned k0a[4] = {pA0.x, pA0.y, pA0.z, pA0.w};
      const unsigned k1a[4] = {pA1.x, pA1.y, pA1.z, pA1.w};
#pragma unroll
      for (int q = 0; q < 4; ++q) {
        const unsigned lo = __builtin_amdgcn_perm(k1a[q], k0a[q], losel);
        const unsigned hi = __builtin_amdgcn_perm(k1a[q], k0a[q], hisel);
        asm("v_dot2_f32_bf16 %0, %1, %2, %0" : "+v"(acc[q * 2]) : "v"(wpk), "v"(lo));
        asm("v_dot2_f32_bf16 %0, %1, %2, %0" : "+v"(acc[q * 2 + 1]) : "v"(wpk), "v"(hi));
      }
      if (more) { uA0 = uB0; uA1 = uB1; pA0 = pB0; pA1 = pB1; }
    }
  }
  // reduce across the 4 edge-groups (same sub = same columns)
#pragma unroll
  for (int off = 16; off < 64; off <<= 1) {
    sw += __shfl_xor(sw, off, 64);
#pragma unroll
    for (int q = 0; q < 8; ++q) acc[q] += __shfl_xor(acc[q], off, 64);
  }
  const float inv = pdeg > 0 ? 1.0f / sw : 0.f;
  float o[8];
#pragma unroll
  for (int q = 0; q < 8; ++q) {
    const float v = acc[q] * inv;
    o[q] = v > 0.f ? v : __expf(v) - 1.f;  // elu alpha=1
  }
  if (lane < 16) {
    float4* op = (float4*)(out + (size_t)node * OD + sub * 8);
    op[0] = make_float4(o[0], o[1], o[2], o[3]);
    op[1] = make_float4(o[4], o[5], o[6], o[7]);
  }
}

extern "C" void kernel_launch(void* const* d_in, const int* in_sizes, int n_in,
                              void* d_out, int out_size, void* d_ws, size_t ws_size,
                              hipStream_t stream) {
  const float* x = (const float*)d_in[0];
  const int* el = (const int*)d_in[1];
  const float* W = (const float*)d_in[2];
  const float* a = (const float*)d_in[3];
  float* out = (float*)d_out;
  char* ws = (char*)d_ws;

  const size_t S = 400384;  // 100000*4 padded to 512
  float* ssrc    = (float*)(ws + 0 * S);
  float* sdst    = (float*)(ws + 1 * S);
  uint2* rc      = (uint2*)(ws + 2 * S);        // 800 KB (spans slots 2+3)
  int* bcur      = (int*)(ws + 4 * S);          // 391 ints
  unsigned short* Wt = (unsigned short*)(ws + 4 * S + 8192);          // 64 KB
  unsigned short* h  = (unsigned short*)(ws + 4 * S + 8192 + 65536);  // 25.6 MB
  unsigned* csrw = (unsigned*)(ws + 4 * S + 8192 + 65536 + (size_t)NN * OD * 2);  // 15.6 MB
  // staging (12.81 MB) lives in d_out scratch space (51.2 MB); consumed by
  // place2_k before aggr_k rewrites every output element.
  unsigned* stage = (unsigned*)d_out;

  prep_wt_k<<<128, 256, 0, stream>>>(W, Wt, bcur);
  fused_k<<<NGB + NBIN, 1024, 0, stream>>>(x, Wt, a, h, ssrc, sdst, el, bcur, stage);
  place2_k<<<NB, 256, 0, stream>>>(stage, bcur, ssrc, sdst, csrw, rc);
  aggr_k<<<NN / 4, 256, 0, stream>>>(h, csrw, rc, out);
}